// Round 11
// baseline (631.900 us; speedup 1.0000x reference)
//
#include <hip/hip_runtime.h>

#define BD 128   // D
#define SL 512   // L
#define NB 4     // B
#define NBLK 512u

__device__ __forceinline__ float rcp_fast(float x) { return __builtin_amdgcn_rcpf(x); }

// Grid-wide spin barrier: 512 blocks x (1024thr, 8 waves/EU) = exactly 2 blocks/CU
// on 256 CUs -> all blocks co-resident by capacity. cnt zeroed host-side per launch.
__device__ __forceinline__ void gbar(unsigned* cnt) {
    __threadfence();
    __syncthreads();
    if (threadIdx.x == 0) {
        atomicAdd(cnt, 1u);
        while (atomicAdd(cnt, 0u) < NBLK) __builtin_amdgcn_s_sleep(2);
    }
    __syncthreads();
    __threadfence();
}

// Fused: Stage A (blocks 0..15: W transpose) | gbar | Stage B (per block: qu/kw for
// its 4 rows; Equ2 -> global (XCD-local), kw -> LDS only) | gbar | Stage C (= R9
// k_attn: paired-rcp scores, no-max softmax, PV). XCD swizzle pins batch b to XCD
// pair {2b,2b+1} for Equ2 L2 locality.
__global__ __launch_bounds__(1024, 8) void k_fused(const float* __restrict__ inp,
                                                   const float* __restrict__ Wu,
                                                   const float* __restrict__ Ww,
                                                   const float* __restrict__ Wv,
                                                   float* __restrict__ Equ2,
                                                   float* __restrict__ WuT,
                                                   float* __restrict__ WwT,
                                                   float* __restrict__ out,
                                                   float* __restrict__ attn,
                                                   unsigned* __restrict__ cnt) {
    __shared__ float s_buf[10912];        // 43.6 KB, unioned across stages
    float*  s_pT = s_buf;                 // [SL][4]  stage C attn weights
    float*  s_ap = s_buf + 2048;          // [8192]   P1 partials / P3 s_fin
    float*  s_ek = s_buf + 2048;          // [4][128] kw->exp (stage B out), read at C-B1
    float*  sx   = s_buf + 2048 + 512;    // [4][BD]  stage B input rows
    float4* s_E  = (float4*)(s_buf + 10240);   // [BD]
    float*  s_u  = s_buf + 10752;         // [BD]
    float*  s_rB = s_buf + 10880;         // [32]

    const int t   = threadIdx.x;
    const int blk = blockIdx.x;
    const int x   = blk & 7;              // XCD (round-robin heuristic)
    const int b   = x >> 1;               // batch pinned to XCD pair
    const int it  = (blk >> 3) * 2 + (x & 1);   // tile 0..127
    const int i0  = it * 4;               // this block's 4 rows (stages B and C)
    const int r0g = b * SL + i0;

    // ================= Stage A: W transpose (blocks 0..15) =================
    if (blk < 16) {
        int idx = blk * 1024 + t;         // 0..16383
        int k = idx >> 7, o = idx & 127;
        WuT[idx] = Wu[o * BD + k];
        WwT[idx] = Ww[o * BD + k];
    }
    gbar(&cnt[0]);

    // ================= Stage B: qu/kw for rows i0..i0+3 =================
    if (t < 512) sx[t] = inp[(size_t)r0g * BD + t];   // coalesced
    __syncthreads();
    if (t < 512) {
        const int o = t & 127, m = (t >> 7) & 1, pr = (t >> 8) & 1;
        const float* WT = m ? WwT : WuT;  // WT[k][o], coalesced, L2-hot
        const float* xA = sx + (pr * 2) * BD;
        const float* xB = xA + BD;
        float acc0 = 0.f, acc1 = 0.f;
        #pragma unroll 4
        for (int k = 0; k < BD; k += 4) { // 16 loads in flight
            float w0 = WT[(k + 0) * BD + o];
            float w1 = WT[(k + 1) * BD + o];
            float w2 = WT[(k + 2) * BD + o];
            float w3 = WT[(k + 3) * BD + o];
            float4 a4 = *(const float4*)&xA[k];
            float4 b4 = *(const float4*)&xB[k];
            acc0 = fmaf(a4.x, w0, acc0); acc0 = fmaf(a4.y, w1, acc0);
            acc0 = fmaf(a4.z, w2, acc0); acc0 = fmaf(a4.w, w3, acc0);
            acc1 = fmaf(b4.x, w0, acc1); acc1 = fmaf(b4.y, w1, acc1);
            acc1 = fmaf(b4.z, w2, acc1); acc1 = fmaf(b4.w, w3, acc1);
        }
        float e0 = __expf(2.f * acc0), e1 = __expf(2.f * acc1);
        if (m == 0) {                     // Equ2 packed, consumed grid-wide
            size_t base = (((size_t)b * 32 + (o >> 2)) * 256 + (it * 2 + pr)) * 8 + (o & 3);
            Equ2[base]     = e0;          // row i0+pr*2,   jj=0
            Equ2[base + 4] = e1;          // row i0+pr*2+1, jj=1
        } else {                          // kw stays in LDS — consumed by THIS block only
            s_ek[(pr * 2 + 0) * 128 + o] = e0;
            s_ek[(pr * 2 + 1) * 128 + o] = e1;
        }
    }
    gbar(&cnt[1]);                        // Equ2 visible grid-wide; s_ek block-local

    // ================= Stage C =================
    if (t < BD) {
        float u = rcp_fast(Wv[t]);
        s_E[t] = make_float4(s_ek[0 * 128 + t] * u, s_ek[1 * 128 + t] * u,
                             s_ek[2 * 128 + t] * u, s_ek[3 * 128 + t] * u);
        s_u[t] = u;
    }
    __syncthreads();                                         // B1

    // ---- Phase 1: paired-rcp ----
    const int jp = t & 255, dg = t >> 8;
    const float4* equ4 = (const float4*)(Equ2 + (size_t)b * BD * SL);
    float a0[4] = {0.f, 0.f, 0.f, 0.f};   // j = 2jp
    float a1[4] = {0.f, 0.f, 0.f, 0.f};   // j = 2jp+1
    #pragma unroll 2
    for (int cc = 0; cc < 8; ++cc) {
        int c = dg * 8 + cc;
        float4 qA = equ4[(c * 256 + jp) * 2 + 0];
        float4 qB = equ4[(c * 256 + jp) * 2 + 1];
        float4 E0 = s_E[c * 4 + 0];
        float4 E1 = s_E[c * 4 + 1];
        float4 E2 = s_E[c * 4 + 2];
        float4 E3 = s_E[c * 4 + 3];
        float4 uu = *(const float4*)&s_u[c * 4];
        float e0[4] = {E0.x, E0.y, E0.z, E0.w};
        float e1[4] = {E1.x, E1.y, E1.z, E1.w};
        float e2[4] = {E2.x, E2.y, E2.z, E2.w};
        float e3[4] = {E3.x, E3.y, E3.z, E3.w};
        #pragma unroll
        for (int i = 0; i < 4; ++i) {
            float xa0 = fmaf(qA.x, e0[i], uu.x);
            float xa1 = fmaf(qA.y, e1[i], uu.y);
            a0[i] = fmaf(xa0 + xa1, rcp_fast(xa0 * xa1), a0[i]);
            float xa2 = fmaf(qA.z, e2[i], uu.z);
            float xa3 = fmaf(qA.w, e3[i], uu.w);
            a0[i] = fmaf(xa2 + xa3, rcp_fast(xa2 * xa3), a0[i]);
            float xb0 = fmaf(qB.x, e0[i], uu.x);
            float xb1 = fmaf(qB.y, e1[i], uu.y);
            a1[i] = fmaf(xb0 + xb1, rcp_fast(xb0 * xb1), a1[i]);
            float xb2 = fmaf(qB.z, e2[i], uu.z);
            float xb3 = fmaf(qB.w, e3[i], uu.w);
            a1[i] = fmaf(xb2 + xb3, rcp_fast(xb2 * xb3), a1[i]);
        }
    }
    __syncthreads();                       // s_ek reads (B1) done before s_ap overwrite
    #pragma unroll
    for (int i = 0; i < 4; ++i) {
        s_ap[((dg * 2 + 0) * 4 + i) * 256 + jp] = a0[i];
        s_ap[((dg * 2 + 1) * 4 + i) * 256 + jp] = a1[i];
    }
    __syncthreads();                                         // B2

    // ---- Phase 2: softmax (no max-shift) ----
    const int j = t & 511, dh = t >> 9, ro = dh * 2;
    const int jpp = j >> 1, jj = j & 1, w8 = j >> 6;
    float af[2];
    #pragma unroll
    for (int ii = 0; ii < 2; ++ii) {
        int r = ro + ii;
        af[ii] = s_ap[((0 * 2 + jj) * 4 + r) * 256 + jpp]
               + s_ap[((1 * 2 + jj) * 4 + r) * 256 + jpp]
               + s_ap[((2 * 2 + jj) * 4 + r) * 256 + jpp]
               + s_ap[((3 * 2 + jj) * 4 + r) * 256 + jpp];
    }
    float p0 = __expf(-2.f * af[0]);
    float p1 = __expf(-2.f * af[1]);
    float sm0 = p0, sm1 = p1;
    #pragma unroll
    for (int off = 32; off > 0; off >>= 1) {
        sm0 += __shfl_xor(sm0, off, 64);
        sm1 += __shfl_xor(sm1, off, 64);
    }
    if ((j & 63) == 0) { s_rB[(ro + 0) * 8 + w8] = sm0; s_rB[(ro + 1) * 8 + w8] = sm1; }
    __syncthreads();                                         // B3
    float n0, n1;
    {
        float4 r0 = *(const float4*)&s_rB[(ro + 0) * 8];
        float4 r1 = *(const float4*)&s_rB[(ro + 0) * 8 + 4];
        n0 = p0 * rcp_fast((r0.x + r0.y) + (r0.z + r0.w) + (r1.x + r1.y) + (r1.z + r1.w));
        float4 s0 = *(const float4*)&s_rB[(ro + 1) * 8];
        float4 s1 = *(const float4*)&s_rB[(ro + 1) * 8 + 4];
        n1 = p1 * rcp_fast((s0.x + s0.y) + (s0.z + s0.w) + (s1.x + s1.y) + (s1.z + s1.w));
    }
    attn[((size_t)b * SL + i0 + ro + 0) * SL + j] = n0;      // coalesced
    attn[((size_t)b * SL + i0 + ro + 1) * SL + j] = n1;
    ((float2*)s_pT)[j * 2 + dh] = make_float2(n0, n1);       // [j][4]
    __syncthreads();                                         // B4

    // ---- Phase 3: out = attn @ inp ----
    const int g  = t >> 6;                  // 16 waves
    const int ln = t & 63;
    const int dq = ln & 31;
    const int rh = ln >> 5;
    const float4* inp4 = (const float4*)(inp + (size_t)b * SL * BD);
    float4 acc0 = make_float4(0.f, 0.f, 0.f, 0.f);
    float4 acc1 = make_float4(0.f, 0.f, 0.f, 0.f);
    #pragma unroll 4
    for (int jjj = 0; jjj < 32; ++jjj) {
        int jr = g * 32 + jjj;
        float4 xv = inp4[jr * 32 + dq];                    // L2 b128
        float2 pp = ((const float2*)s_pT)[jr * 2 + rh];    // 2-addr LDS broadcast
        acc0.x = fmaf(pp.x, xv.x, acc0.x); acc0.y = fmaf(pp.x, xv.y, acc0.y);
        acc0.z = fmaf(pp.x, xv.z, acc0.z); acc0.w = fmaf(pp.x, xv.w, acc0.w);
        acc1.x = fmaf(pp.y, xv.x, acc1.x); acc1.y = fmaf(pp.y, xv.y, acc1.y);
        acc1.z = fmaf(pp.y, xv.z, acc1.z); acc1.w = fmaf(pp.y, xv.w, acc1.w);
    }
    float* s_fin = s_ap;                    // [16][4][BD]
    *(float4*)&s_fin[((g * 4) + rh * 2 + 0) * BD + dq * 4] = acc0;
    *(float4*)&s_fin[((g * 4) + rh * 2 + 1) * BD + dq * 4] = acc1;
    __syncthreads();                                         // B5
    if (t < 512) {
        int row = t >> 7, d = t & 127;
        float s = 0.f;
        #pragma unroll
        for (int gg = 0; gg < 16; ++gg)
            s += s_fin[(gg * 4 + row) * BD + d];           // conflict-free
        out[((size_t)b * SL + i0 + row) * BD + d] = s;     // coalesced
    }
}

extern "C" void kernel_launch(void* const* d_in, const int* in_sizes, int n_in,
                              void* d_out, int out_size, void* d_ws, size_t ws_size,
                              hipStream_t stream) {
    const float* inp = (const float*)d_in[0];
    const float* Wu  = (const float*)d_in[1];
    const float* Ww  = (const float*)d_in[2];
    const float* Wv  = (const float*)d_in[3];

    float* out  = (float*)d_out;
    float* attn = out + (size_t)NB * SL * BD;     // out (B,L,D) then attn (B,L,L)

    float*    ws   = (float*)d_ws;
    float*    Equ2 = ws;                          // (B, D/4, L/2, 8) packed exp(2*qu)
    float*    WuT  = Equ2 + (size_t)NB * BD * SL; // 16384
    float*    WwT  = WuT + BD * BD;               // 16384
    unsigned* cnt  = (unsigned*)(WwT + BD * BD);  // 2 barrier counters

    hipMemsetAsync(cnt, 0, 2 * sizeof(unsigned), stream);
    k_fused<<<NBLK, 1024, 0, stream>>>(inp, Wu, Ww, Wv, Equ2, WuT, WwT, out, attn, cnt);
}

// Round 12
// 108.619 us; speedup vs baseline: 5.8176x; 5.8176x over previous
//
#include <hip/hip_runtime.h>

#define BD 128   // D
#define SL 512   // L
#define NB 4     // B

__device__ __forceinline__ float rcp_fast(float x) { return __builtin_amdgcn_rcpf(x); }

// K1: qu only. 1024 blocks x 256 thr (4 blocks/CU). Block = (b, 2 rows), XCD-pinned.
// Thread (o = t&127, row = t>>7): dot(inp[b,row], Wu[o]) with DIRECT per-thread row
// reads of Wu (no transpose kernel needed; 64KB matrix, L1/L2-resident).
// Equ2 packed [b][d>>2][j>>1][(j&1)*4 + (d&3)].
__global__ __launch_bounds__(256) void k_qu(const float* __restrict__ inp,
                                            const float* __restrict__ Wu,
                                            float* __restrict__ Equ2) {
    __shared__ float sx[2][BD];
    const int t   = threadIdx.x;
    const int blk = blockIdx.x;
    const int x   = blk & 7;                 // XCD (round-robin heuristic)
    const int b   = x >> 1;                  // batch pinned to XCD pair
    const int rp  = (blk >> 3) * 2 + (x & 1);   // row-pair 0..255
    const int r0  = b * SL + rp * 2;

    sx[t >> 7][t & 127] = inp[(size_t)r0 * BD + t];   // coalesced 2 rows
    __syncthreads();

    const int o = t & 127, rr = t >> 7;
    const float* wr = Wu + o * BD;           // per-thread contiguous row
    const float* xr = &sx[rr][0];
    float acc = 0.f;
    #pragma unroll 8
    for (int k = 0; k < BD; k += 4) {
        float4 w4 = *(const float4*)&wr[k];  // L1-friendly (same line 1x per 16 floats)
        float4 x4 = *(const float4*)&xr[k];  // LDS b128 broadcast
        acc = fmaf(x4.x, w4.x, acc); acc = fmaf(x4.y, w4.y, acc);
        acc = fmaf(x4.z, w4.z, acc); acc = fmaf(x4.w, w4.w, acc);
    }
    // row gl = rp*2 + rr; jj = gl&1 = rr
    Equ2[(((size_t)b * 32 + (o >> 2)) * 256 + rp) * 8 + rr * 4 + (o & 3)] =
        __expf(2.f * acc);
}

// K2: block = (b, 4 query rows), 1024 threads, 2 blocks/CU, XCD-pinned.
// Prologue: compute THIS block's 4 kw rows in-block (dot vs direct Ww rows) -> s_ek
// (Ekw never touches global). Then R9 body: paired-rcp scores, no-max softmax, PV.
__global__ __launch_bounds__(1024, 8) void k_attn(const float* __restrict__ inp,
                                                  const float* __restrict__ Ww,
                                                  const float* __restrict__ Wv,
                                                  const float* __restrict__ Equ2,
                                                  float* __restrict__ out,
                                                  float* __restrict__ attn) {
    __shared__ float s_buf[10912];        // 43.6 KB
    float*  s_pT = s_buf;                 // [SL][4]  attn weights
    float*  s_ap = s_buf + 2048;          // [8192]   P1 partials / P3 s_fin
    float*  s_ek = s_buf + 2048;          // [4][128] exp(2*kw) (dead after s_E build)
    float*  sx   = s_buf + 2560;          // [4][BD]  inp rows   (dead after prologue)
    float4* s_E  = (float4*)(s_buf + 10240);   // [BD]
    float*  s_u  = s_buf + 10752;         // [BD]
    float*  s_rB = s_buf + 10880;         // [32]

    const int t   = threadIdx.x;
    const int blk = blockIdx.x;
    const int x   = blk & 7;              // XCD
    const int b   = x >> 1;               // batch pinned to XCD pair
    const int it  = (blk >> 3) * 2 + (x & 1);   // tile 0..127
    const int i0  = it * 4;
    const int r0g = b * SL + i0;

    // ---- Prologue: kw for rows i0..i0+3, LDS-only ----
    if (t < 512) sx[t] = inp[(size_t)r0g * BD + t];   // coalesced
    __syncthreads();
    if (t < 512) {
        const int o = t & 127, r = t >> 7;
        const float* wr = Ww + o * BD;    // per-thread contiguous row
        const float* xr = sx + r * BD;
        float acc = 0.f;
        #pragma unroll 8
        for (int k = 0; k < BD; k += 4) {
            float4 w4 = *(const float4*)&wr[k];
            float4 x4 = *(const float4*)&xr[k];
            acc = fmaf(x4.x, w4.x, acc); acc = fmaf(x4.y, w4.y, acc);
            acc = fmaf(x4.z, w4.z, acc); acc = fmaf(x4.w, w4.w, acc);
        }
        s_ek[r * 128 + o] = __expf(2.f * acc);
    }
    __syncthreads();

    if (t < BD) {
        float u = rcp_fast(Wv[t]);
        s_E[t] = make_float4(s_ek[0 * 128 + t] * u, s_ek[1 * 128 + t] * u,
                             s_ek[2 * 128 + t] * u, s_ek[3 * 128 + t] * u);
        s_u[t] = u;
    }
    __syncthreads();                                         // B1 (s_ek/sx dead now)

    // ---- Phase 1: paired-rcp ----
    const int jp = t & 255, dg = t >> 8;
    const float4* equ4 = (const float4*)(Equ2 + (size_t)b * BD * SL);
    float a0[4] = {0.f, 0.f, 0.f, 0.f};   // j = 2jp
    float a1[4] = {0.f, 0.f, 0.f, 0.f};   // j = 2jp+1
    #pragma unroll 2
    for (int cc = 0; cc < 8; ++cc) {
        int c = dg * 8 + cc;
        float4 qA = equ4[(c * 256 + jp) * 2 + 0];
        float4 qB = equ4[(c * 256 + jp) * 2 + 1];
        float4 E0 = s_E[c * 4 + 0];
        float4 E1 = s_E[c * 4 + 1];
        float4 E2 = s_E[c * 4 + 2];
        float4 E3 = s_E[c * 4 + 3];
        float4 uu = *(const float4*)&s_u[c * 4];
        float e0[4] = {E0.x, E0.y, E0.z, E0.w};
        float e1[4] = {E1.x, E1.y, E1.z, E1.w};
        float e2[4] = {E2.x, E2.y, E2.z, E2.w};
        float e3[4] = {E3.x, E3.y, E3.z, E3.w};
        #pragma unroll
        for (int i = 0; i < 4; ++i) {
            float xa0 = fmaf(qA.x, e0[i], uu.x);
            float xa1 = fmaf(qA.y, e1[i], uu.y);
            a0[i] = fmaf(xa0 + xa1, rcp_fast(xa0 * xa1), a0[i]);
            float xa2 = fmaf(qA.z, e2[i], uu.z);
            float xa3 = fmaf(qA.w, e3[i], uu.w);
            a0[i] = fmaf(xa2 + xa3, rcp_fast(xa2 * xa3), a0[i]);
            float xb0 = fmaf(qB.x, e0[i], uu.x);
            float xb1 = fmaf(qB.y, e1[i], uu.y);
            a1[i] = fmaf(xb0 + xb1, rcp_fast(xb0 * xb1), a1[i]);
            float xb2 = fmaf(qB.z, e2[i], uu.z);
            float xb3 = fmaf(qB.w, e3[i], uu.w);
            a1[i] = fmaf(xb2 + xb3, rcp_fast(xb2 * xb3), a1[i]);
        }
    }
    #pragma unroll
    for (int i = 0; i < 4; ++i) {
        s_ap[((dg * 2 + 0) * 4 + i) * 256 + jp] = a0[i];     // conflict-free
        s_ap[((dg * 2 + 1) * 4 + i) * 256 + jp] = a1[i];
    }
    __syncthreads();                                         // B2

    // ---- Phase 2: softmax (no max-shift) ----
    const int j = t & 511, dh = t >> 9, ro = dh * 2;
    const int jpp = j >> 1, jj = j & 1, w8 = j >> 6;
    float af[2];
    #pragma unroll
    for (int ii = 0; ii < 2; ++ii) {
        int r = ro + ii;
        af[ii] = s_ap[((0 * 2 + jj) * 4 + r) * 256 + jpp]
               + s_ap[((1 * 2 + jj) * 4 + r) * 256 + jpp]
               + s_ap[((2 * 2 + jj) * 4 + r) * 256 + jpp]
               + s_ap[((3 * 2 + jj) * 4 + r) * 256 + jpp];
    }
    float p0 = __expf(-2.f * af[0]);
    float p1 = __expf(-2.f * af[1]);
    float sm0 = p0, sm1 = p1;
    #pragma unroll
    for (int off = 32; off > 0; off >>= 1) {
        sm0 += __shfl_xor(sm0, off, 64);
        sm1 += __shfl_xor(sm1, off, 64);
    }
    if ((j & 63) == 0) { s_rB[(ro + 0) * 8 + w8] = sm0; s_rB[(ro + 1) * 8 + w8] = sm1; }
    __syncthreads();                                         // B3
    float n0, n1;
    {
        float4 r0 = *(const float4*)&s_rB[(ro + 0) * 8];
        float4 r1 = *(const float4*)&s_rB[(ro + 0) * 8 + 4];
        n0 = p0 * rcp_fast((r0.x + r0.y) + (r0.z + r0.w) + (r1.x + r1.y) + (r1.z + r1.w));
        float4 s0 = *(const float4*)&s_rB[(ro + 1) * 8];
        float4 s1 = *(const float4*)&s_rB[(ro + 1) * 8 + 4];
        n1 = p1 * rcp_fast((s0.x + s0.y) + (s0.z + s0.w) + (s1.x + s1.y) + (s1.z + s1.w));
    }
    attn[((size_t)b * SL + i0 + ro + 0) * SL + j] = n0;      // coalesced
    attn[((size_t)b * SL + i0 + ro + 1) * SL + j] = n1;
    ((float2*)s_pT)[j * 2 + dh] = make_float2(n0, n1);       // [j][4]
    __syncthreads();                                         // B4

    // ---- Phase 3: out = attn @ inp ----
    const int g  = t >> 6;                  // 16 waves
    const int ln = t & 63;
    const int dq = ln & 31;
    const int rh = ln >> 5;
    const float4* inp4 = (const float4*)(inp + (size_t)b * SL * BD);
    float4 acc0 = make_float4(0.f, 0.f, 0.f, 0.f);
    float4 acc1 = make_float4(0.f, 0.f, 0.f, 0.f);
    #pragma unroll 4
    for (int jjj = 0; jjj < 32; ++jjj) {
        int jr = g * 32 + jjj;
        float4 xv = inp4[jr * 32 + dq];                    // L2 b128
        float2 pp = ((const float2*)s_pT)[jr * 2 + rh];    // 2-addr LDS broadcast
        acc0.x = fmaf(pp.x, xv.x, acc0.x); acc0.y = fmaf(pp.x, xv.y, acc0.y);
        acc0.z = fmaf(pp.x, xv.z, acc0.z); acc0.w = fmaf(pp.x, xv.w, acc0.w);
        acc1.x = fmaf(pp.y, xv.x, acc1.x); acc1.y = fmaf(pp.y, xv.y, acc1.y);
        acc1.z = fmaf(pp.y, xv.z, acc1.z); acc1.w = fmaf(pp.y, xv.w, acc1.w);
    }
    float* s_fin = s_ap;                    // [16][4][BD]
    *(float4*)&s_fin[((g * 4) + rh * 2 + 0) * BD + dq * 4] = acc0;
    *(float4*)&s_fin[((g * 4) + rh * 2 + 1) * BD + dq * 4] = acc1;
    __syncthreads();                                         // B5
    if (t < 512) {
        int row = t >> 7, d = t & 127;
        float s = 0.f;
        #pragma unroll
        for (int gg = 0; gg < 16; ++gg)
            s += s_fin[(gg * 4 + row) * BD + d];           // conflict-free
        out[((size_t)b * SL + i0 + row) * BD + d] = s;     // coalesced
    }
}

extern "C" void kernel_launch(void* const* d_in, const int* in_sizes, int n_in,
                              void* d_out, int out_size, void* d_ws, size_t ws_size,
                              hipStream_t stream) {
    const float* inp = (const float*)d_in[0];
    const float* Wu  = (const float*)d_in[1];
    const float* Ww  = (const float*)d_in[2];
    const float* Wv  = (const float*)d_in[3];

    float* out  = (float*)d_out;
    float* attn = out + (size_t)NB * SL * BD;     // out (B,L,D) then attn (B,L,L)

    float* Equ2 = (float*)d_ws;                   // (B, D/4, L/2, 8) packed exp(2*qu)

    k_qu  <<<NB * SL / 2, 256, 0, stream>>>(inp, Wu, Equ2);
    k_attn<<<NB * SL / 4, 1024, 0, stream>>>(inp, Ww, Wv, Equ2, out, attn);
}

// Round 13
// 88.907 us; speedup vs baseline: 7.1075x; 1.2217x over previous
//
#include <hip/hip_runtime.h>

#define BD 128   // D
#define SL 512   // L
#define NB 4     // B

__device__ __forceinline__ float rcp_fast(float x) { return __builtin_amdgcn_rcpf(x); }

// K0: transpose Wu, Ww (row-major (out,in)) -> WT[k][o]. 64 blocks, trivial.
// (Merging this into k_qk via direct row reads was tried in R12: -20us regression —
//  per-thread-contiguous rows are uncoalesced, 64 L1 lines/instr. Keep k_tr.)
__global__ __launch_bounds__(256) void k_tr(const float* __restrict__ Wu,
                                            const float* __restrict__ Ww,
                                            float* __restrict__ WuT,
                                            float* __restrict__ WwT) {
    int idx = blockIdx.x * 256 + threadIdx.x;   // 0..16383
    int k = idx >> 7, o = idx & 127;
    WuT[idx] = Wu[o * BD + k];
    WwT[idx] = Ww[o * BD + k];
}

// K1: qu = inp@Wu.T, kw = inp@Ww.T. 2 rows/block, 1024 blocks (4/CU).
// XCD-aware swizzle: batch b pinned to XCD pair {2b, 2b+1} (blk%8 = XCD heuristic)
// so Equ2/Ekw writes land in the L2 that k_attn will read them from.
// Equ2 packed [b][d>>2][j>>1][(j&1)*4 + (d&3)]: k_attn reads a j-pair as 2 b128.
__global__ __launch_bounds__(256) void k_qk(const float* __restrict__ inp,
                                            const float* __restrict__ WuT,
                                            const float* __restrict__ WwT,
                                            float* __restrict__ Equ2,
                                            float* __restrict__ Ekw) {
    __shared__ float sx[2][BD];
    const int t = threadIdx.x, m = t >> 7, o = t & 127;
    const int blk = blockIdx.x;
    const int x   = blk & 7;                // XCD (round-robin heuristic)
    const int b   = x >> 1;                 // batch pinned to XCD pair
    const int rp  = (blk >> 3) * 2 + (x & 1);   // row-pair 0..255
    const int r0  = b * SL + rp * 2;        // global row (even)
    const int jp  = rp;

    sx[t >> 7][t & 127] = inp[(size_t)r0 * BD + t];   // coalesced 512 floats
    __syncthreads();

    const float* WT = m ? WwT : WuT;        // WT[k][o], coalesced + L2-hot
    float acc0 = 0.f, acc1 = 0.f;
    #pragma unroll 4
    for (int k = 0; k < BD; k += 4) {       // 16 loads in flight
        float w0 = WT[(k + 0) * BD + o];
        float w1 = WT[(k + 1) * BD + o];
        float w2 = WT[(k + 2) * BD + o];
        float w3 = WT[(k + 3) * BD + o];
        float4 x0 = *(const float4*)&sx[0][k];
        float4 x1 = *(const float4*)&sx[1][k];
        acc0 = fmaf(x0.x, w0, acc0); acc0 = fmaf(x0.y, w1, acc0);
        acc0 = fmaf(x0.z, w2, acc0); acc0 = fmaf(x0.w, w3, acc0);
        acc1 = fmaf(x1.x, w0, acc1); acc1 = fmaf(x1.y, w1, acc1);
        acc1 = fmaf(x1.z, w2, acc1); acc1 = fmaf(x1.w, w3, acc1);
    }

    if (m == 0) {
        size_t base = (((size_t)b * 32 + (o >> 2)) * 256 + jp) * 8 + (o & 3);
        Equ2[base]     = __expf(2.f * acc0);   // jj=0
        Equ2[base + 4] = __expf(2.f * acc1);   // jj=1
    } else {
        Ekw[(size_t)(r0 + 0) * BD + o] = __expf(2.f * acc0);
        Ekw[(size_t)(r0 + 1) * BD + o] = __expf(2.f * acc1);
    }
}

// K2: block = (b, 4 query rows), 1024 threads, 2 blocks/CU, XCD-pinned.
// P1 paired-rcp: wv/(1+qe) = 1/x, x = fma(q, E, u), E = e*u, u = 1/wv;
//   1/x0 + 1/x1 = (x0+x1)*rcp(x0*x1) -> one rcp per two d.
// P2: softmax WITHOUT max-shift (|2a| <= 2*sum|wv| ~ 18, exp in fp32 range).
// P3: 16 j-chunk waves, b128 staging, 16-way LDS reduce.
__global__ __launch_bounds__(1024, 8) void k_attn(const float* __restrict__ inp,
                                                  const float* __restrict__ Wv,
                                                  const float* __restrict__ Equ2,
                                                  const float* __restrict__ Ekw,
                                                  float* __restrict__ out,
                                                  float* __restrict__ attn) {
    __shared__ float  s_pT[SL * 4];        // 8 KB  attn weights [j][4 rows]
    __shared__ float  s_ap[8192];          // 32 KB P1 partials; P3 s_fin
    __shared__ float4 s_E[BD];             // 2 KB  {e_i*u} per d, i=0..3
    __shared__ float  s_u[BD];             // 0.5 KB 1/wv
    __shared__ float  s_rB[4 * 8];         // sum-reduce

    const int t   = threadIdx.x;
    const int blk = blockIdx.x;
    const int x   = blk & 7;                // XCD
    const int b   = x >> 1;                 // batch pinned to XCD pair
    const int it  = (blk >> 3) * 2 + (x & 1);   // i-tile 0..127
    const int i0  = it * 4;

    if (t < BD) {
        const float* ek = Ekw + ((size_t)b * SL + i0) * BD + t;
        float u = rcp_fast(Wv[t]);
        s_E[t] = make_float4(ek[0] * u, ek[BD] * u, ek[2 * BD] * u, ek[3 * BD] * u);
        s_u[t] = u;
    }
    __syncthreads();                                         // B1

    // ---- Phase 1 ----
    const int jp = t & 255, dg = t >> 8;
    const float4* equ4 = (const float4*)(Equ2 + (size_t)b * BD * SL);
    float a0[4] = {0.f, 0.f, 0.f, 0.f};   // j = 2jp
    float a1[4] = {0.f, 0.f, 0.f, 0.f};   // j = 2jp+1
    #pragma unroll 2
    for (int cc = 0; cc < 8; ++cc) {
        int c = dg * 8 + cc;
        float4 qA = equ4[(c * 256 + jp) * 2 + 0];   // j=2jp,   d=4c..4c+3
        float4 qB = equ4[(c * 256 + jp) * 2 + 1];   // j=2jp+1
        float4 E0 = s_E[c * 4 + 0];        // wave-uniform b128 broadcasts
        float4 E1 = s_E[c * 4 + 1];
        float4 E2 = s_E[c * 4 + 2];
        float4 E3 = s_E[c * 4 + 3];
        float4 uu = *(const float4*)&s_u[c * 4];
        float e0[4] = {E0.x, E0.y, E0.z, E0.w};
        float e1[4] = {E1.x, E1.y, E1.z, E1.w};
        float e2[4] = {E2.x, E2.y, E2.z, E2.w};
        float e3[4] = {E3.x, E3.y, E3.z, E3.w};
        #pragma unroll
        for (int i = 0; i < 4; ++i) {
            float xa0 = fmaf(qA.x, e0[i], uu.x);
            float xa1 = fmaf(qA.y, e1[i], uu.y);
            a0[i] = fmaf(xa0 + xa1, rcp_fast(xa0 * xa1), a0[i]);
            float xa2 = fmaf(qA.z, e2[i], uu.z);
            float xa3 = fmaf(qA.w, e3[i], uu.w);
            a0[i] = fmaf(xa2 + xa3, rcp_fast(xa2 * xa3), a0[i]);
            float xb0 = fmaf(qB.x, e0[i], uu.x);
            float xb1 = fmaf(qB.y, e1[i], uu.y);
            a1[i] = fmaf(xb0 + xb1, rcp_fast(xb0 * xb1), a1[i]);
            float xb2 = fmaf(qB.z, e2[i], uu.z);
            float xb3 = fmaf(qB.w, e3[i], uu.w);
            a1[i] = fmaf(xb2 + xb3, rcp_fast(xb2 * xb3), a1[i]);
        }
    }
    #pragma unroll
    for (int i = 0; i < 4; ++i) {
        s_ap[((dg * 2 + 0) * 4 + i) * 256 + jp] = a0[i];     // conflict-free
        s_ap[((dg * 2 + 1) * 4 + i) * 256 + jp] = a1[i];
    }
    __syncthreads();                                         // B2

    // ---- Phase 2: softmax over j of score = -2a, no max-shift ----
    const int j = t & 511, dh = t >> 9, ro = dh * 2;
    const int jpp = j >> 1, jj = j & 1, w8 = j >> 6;
    float af[2];
    #pragma unroll
    for (int ii = 0; ii < 2; ++ii) {
        int r = ro + ii;
        af[ii] = s_ap[((0 * 2 + jj) * 4 + r) * 256 + jpp]
               + s_ap[((1 * 2 + jj) * 4 + r) * 256 + jpp]
               + s_ap[((2 * 2 + jj) * 4 + r) * 256 + jpp]
               + s_ap[((3 * 2 + jj) * 4 + r) * 256 + jpp];
    }
    float p0 = __expf(-2.f * af[0]);
    float p1 = __expf(-2.f * af[1]);
    float sm0 = p0, sm1 = p1;
    #pragma unroll
    for (int off = 32; off > 0; off >>= 1) {
        sm0 += __shfl_xor(sm0, off, 64);
        sm1 += __shfl_xor(sm1, off, 64);
    }
    if ((j & 63) == 0) { s_rB[(ro + 0) * 8 + w8] = sm0; s_rB[(ro + 1) * 8 + w8] = sm1; }
    __syncthreads();                                         // B3
    float n0, n1;
    {
        float4 r0 = *(const float4*)&s_rB[(ro + 0) * 8];
        float4 r1 = *(const float4*)&s_rB[(ro + 0) * 8 + 4];
        n0 = p0 * rcp_fast((r0.x + r0.y) + (r0.z + r0.w) + (r1.x + r1.y) + (r1.z + r1.w));
        float4 s0 = *(const float4*)&s_rB[(ro + 1) * 8];
        float4 s1 = *(const float4*)&s_rB[(ro + 1) * 8 + 4];
        n1 = p1 * rcp_fast((s0.x + s0.y) + (s0.z + s0.w) + (s1.x + s1.y) + (s1.z + s1.w));
    }
    attn[((size_t)b * SL + i0 + ro + 0) * SL + j] = n0;      // coalesced
    attn[((size_t)b * SL + i0 + ro + 1) * SL + j] = n1;
    ((float2*)s_pT)[j * 2 + dh] = make_float2(n0, n1);       // [j][4]
    __syncthreads();                                         // B4

    // ---- Phase 3: out = attn @ inp; wave g covers j = g*32..g*32+31 ----
    const int g  = t >> 6;                  // 16 waves
    const int ln = t & 63;
    const int dq = ln & 31;                 // d-quad
    const int rh = ln >> 5;                 // row pair
    const float4* inp4 = (const float4*)(inp + (size_t)b * SL * BD);
    float4 acc0 = make_float4(0.f, 0.f, 0.f, 0.f);
    float4 acc1 = make_float4(0.f, 0.f, 0.f, 0.f);
    #pragma unroll 4
    for (int jjj = 0; jjj < 32; ++jjj) {
        int jr = g * 32 + jjj;
        float4 xv = inp4[jr * 32 + dq];                    // L2-local b128
        float2 pp = ((const float2*)s_pT)[jr * 2 + rh];    // 2-addr LDS broadcast
        acc0.x = fmaf(pp.x, xv.x, acc0.x); acc0.y = fmaf(pp.x, xv.y, acc0.y);
        acc0.z = fmaf(pp.x, xv.z, acc0.z); acc0.w = fmaf(pp.x, xv.w, acc0.w);
        acc1.x = fmaf(pp.y, xv.x, acc1.x); acc1.y = fmaf(pp.y, xv.y, acc1.y);
        acc1.z = fmaf(pp.y, xv.z, acc1.z); acc1.w = fmaf(pp.y, xv.w, acc1.w);
    }
    float* s_fin = s_ap;                    // [16][4][BD] overlays s_ap
    *(float4*)&s_fin[((g * 4) + rh * 2 + 0) * BD + dq * 4] = acc0;
    *(float4*)&s_fin[((g * 4) + rh * 2 + 1) * BD + dq * 4] = acc1;
    __syncthreads();                                         // B5
    if (t < 512) {
        int row = t >> 7, d = t & 127;
        float s = 0.f;
        #pragma unroll
        for (int gg = 0; gg < 16; ++gg)
            s += s_fin[(gg * 4 + row) * BD + d];           // conflict-free
        out[((size_t)b * SL + i0 + row) * BD + d] = s;     // coalesced
    }
}

extern "C" void kernel_launch(void* const* d_in, const int* in_sizes, int n_in,
                              void* d_out, int out_size, void* d_ws, size_t ws_size,
                              hipStream_t stream) {
    const float* inp = (const float*)d_in[0];
    const float* Wu  = (const float*)d_in[1];
    const float* Ww  = (const float*)d_in[2];
    const float* Wv  = (const float*)d_in[3];

    float* out  = (float*)d_out;
    float* attn = out + (size_t)NB * SL * BD;     // out (B,L,D) then attn (B,L,L)

    float* ws   = (float*)d_ws;
    float* Equ2 = ws;                             // (B, D/4, L/2, 8) packed exp(2*qu)
    float* Ekw  = Equ2 + (size_t)NB * BD * SL;    // (B, L, D) exp(2*kw)
    float* WuT  = Ekw + (size_t)NB * SL * BD;
    float* WwT  = WuT + BD * BD;

    k_tr  <<<BD * BD / 256, 256, 0, stream>>>(Wu, Ww, WuT, WwT);
    k_qk  <<<NB * SL / 2, 256, 0, stream>>>(inp, WuT, WwT, Equ2, Ekw);
    k_attn<<<NB * SL / 4, 1024, 0, stream>>>(inp, Wv, Equ2, Ekw, out, attn);
}